// Round 17
// baseline (49.252 us; speedup 1.0000x reference)
//
#include <hip/hip_runtime.h>

typedef __attribute__((ext_vector_type(8))) __bf16 bf16x8;
typedef __attribute__((ext_vector_type(4))) __bf16 bf16x4;
typedef __attribute__((ext_vector_type(4))) float f32x4;
typedef __attribute__((ext_vector_type(2))) float f32x2;

#define DI 512
#define DO 512
#define XROW (128 * DI)
#define OROW (128 * DO)
#define BK 32
#define BOFF 8192            // buf: A bf16 [128][32] 8 KB | B bf16 [128][32] 8 KB
#define BUFSZ 16384

#define LGKM0()  asm volatile("s_waitcnt lgkmcnt(0)" ::: "memory")
#define SBAR()   __builtin_amdgcn_s_barrier()
#define SCHED0() __builtin_amdgcn_sched_barrier(0)

// Occupancy experiment: acc 64 -> 32 (wave tile 64x32) buys 3 blocks/CU
// (24 waves, 3 independent barrier domains) vs the 2-domain 16-wave plateau
// every 64x64 variant (R10..R15) was stuck at. launch_bounds(512,6): reg cap
// 85; nominal demand ~80 (32 AGPR acc + 16 staging + 12 frags + ~20 misc).
__global__ __launch_bounds__(512, 6)
void nlinear_mfma(const float* __restrict__ xp, const float* __restrict__ wp,
                  const float* __restrict__ bp, float* __restrict__ op) {
  // XCD swizzle: 1024 blocks, 128/XCD; one n's 8 tiles stay on one XCD
  int blk = blockIdx.x;
  int L = ((blk & 7) << 7) + (blk >> 3);
  int n = L >> 3, mt = (L >> 2) & 1, ot = L & 3;
  int mBase = mt << 7, oBase = ot << 7;      // block tile: 128m x 128o

  __shared__ char lds[2 * BUFSZ];            // 32 KB -> 3 blocks/CU = 96 KB

  int tid = threadIdx.x, lane = tid & 63, wid = tid >> 6;
  int wm = (wid >> 2) << 6, wn = (wid & 3) << 5;   // wave tile 64m x 32o
  int l16 = lane & 15, l4 = lane >> 4;

  // A staging (R15-proven): thread t -> m-row t>>2, k-oct (t&3)*8;
  // 2 x f32x4 loads, 1 b128 swizzled write. A LDS [128][32] bf16, 64 B/row,
  // phys slot = aks ^ ((row>>1)&3) on write and read.
  int arow = tid >> 2, aks = tid & 3;
  const float* aSrc = xp + (size_t)(mBase + arow) * XROW + n * DI + aks * 8;
  int aWr = arow * 64 + ((aks ^ ((arow >> 1) & 3)) << 4);

  f32x4 aRv[2];
  auto loadA = [&](int kt) {
    aRv[0] = *(const f32x4*)(aSrc + kt * BK);
    aRv[1] = *(const f32x4*)(aSrc + kt * BK + 4);
  };
  auto writeA = [&](int bufOff) {
    bf16x8 v;
    #pragma unroll
    for (int e = 0; e < 8; ++e) v[e] = (__bf16)aRv[e >> 2][e & 3];
    *(bf16x8*)(lds + bufOff + aWr) = v;
  };

  // B staging: thread t -> o-pair {2*(t&63), +1}, k-quad (t>>6)*4;
  // 4 x f32x2 loads (512B/wave per k-row), 2 x b64 writes into half-slots.
  // B LDS [128 o][32 k] bf16: slot s holds k [8s,8s+8); thread's k-quad is
  // half of slot bkg>>1; phys slot = (bkg>>1) ^ ((o>>1)&3).
  int bo2 = (tid & 63) << 1, bkg = tid >> 6;       // bkg 0..7
  const float* bSrc = wp + ((size_t)n * DI + (bkg << 2)) * DO + oBase + bo2;
  int bslotx = ((bkg >> 1) << 4) ;
  int bhalf = (bkg & 1) << 3;
  int bWr0 = BOFF + (bo2)     * 64 + ((bslotx) ^ (((bo2 >> 1) & 3) << 4)) + bhalf;
  int bWr1 = BOFF + (bo2 + 1) * 64 + ((bslotx) ^ (((bo2 >> 1) & 3) << 4)) + bhalf;

  f32x2 bRv[4];
  auto loadB = [&](int kt) {
    #pragma unroll
    for (int j = 0; j < 4; ++j)
      bRv[j] = *(const f32x2*)(bSrc + (size_t)(kt * BK + j) * DO);
  };
  auto writeB = [&](int bufOff) {
    bf16x4 v0, v1;
    #pragma unroll
    for (int j = 0; j < 4; ++j) { v0[j] = (__bf16)bRv[j].x; v1[j] = (__bf16)bRv[j].y; }
    *(bf16x4*)(lds + bufOff + bWr0) = v0;
    *(bf16x4*)(lds + bufOff + bWr1) = v1;
  };

  f32x4 acc[4][2];
  #pragma unroll
  for (int i = 0; i < 4; ++i)
    #pragma unroll
    for (int j = 0; j < 2; ++j)
      acc[i][j] = f32x4{0.f, 0.f, 0.f, 0.f};

  // i-outer: bfr[2] resident (8 regs), af transient (4 regs); 6 b128/iter.
  bf16x8 bfr[2];
  auto loadBfr = [&](int bufOff) {
    #pragma unroll
    for (int j = 0; j < 2; ++j) {
      int row = wn + j * 16 + l16;
      int slot = l4 ^ ((row >> 1) & 3);
      bfr[j] = *(const bf16x8*)(lds + bufOff + BOFF + row * 64 + slot * 16);
    }
  };
  auto computeI = [&](int bufOff, int i) {
    int row = wm + i * 16 + l16;
    int slot = l4 ^ ((row >> 1) & 3);
    bf16x8 af = *(const bf16x8*)(lds + bufOff + row * 64 + slot * 16);
    acc[i][0] = __builtin_amdgcn_mfma_f32_16x16x32_bf16(af, bfr[0], acc[i][0], 0, 0, 0);
    acc[i][1] = __builtin_amdgcn_mfma_f32_16x16x32_bf16(af, bfr[1], acc[i][1], 0, 0, 0);
  };

  float bi[2];
  #pragma unroll
  for (int j = 0; j < 2; ++j)
    bi[j] = bp[n * DO + oBase + wn + j * 16 + l16];

  // ---- prologue: buf0 staged; tile1 loads in flight across the barrier ----
  loadA(0); loadB(0);
  writeA(0); writeB(0);        // auto-wait tile0 regs
  loadA(1); loadB(1);
  SCHED0(); LGKM0(); SBAR(); SCHED0();

  // iter kt (R15 schedule): write tile kt+1 (regs aged ~1 iter) -> nxt;
  // issue tile kt+2 loads; compute cur. No manual vmcnt.
  for (int kt = 0; kt < 16; ++kt) {
    int cur = (kt & 1) * BUFSZ, nxt = cur ^ BUFSZ;
    if (kt < 15) { writeA(nxt); writeB(nxt); }
    if (kt < 14) { loadA(kt + 2); loadB(kt + 2); }
    SCHED0();
    loadBfr(cur);
    computeI(cur, 0);
    computeI(cur, 1);
    computeI(cur, 2);
    computeI(cur, 3);
    if (kt < 15) { SCHED0(); LGKM0(); SBAR(); SCHED0(); }
  }

  // epilogue: D layout col = lane&15, row = (lane>>4)*4 + r (m89-verified)
  #pragma unroll
  for (int i = 0; i < 4; ++i) {
    #pragma unroll
    for (int j = 0; j < 2; ++j) {
      #pragma unroll
      for (int r = 0; r < 4; ++r) {
        int m = mBase + wm + i * 16 + l4 * 4 + r;
        int o = oBase + wn + j * 16 + l16;
        op[(size_t)m * OROW + n * DO + o] = acc[i][j][r] + bi[j];
      }
    }
  }
}

extern "C" void kernel_launch(void* const* d_in, const int* in_sizes, int n_in,
                              void* d_out, int out_size, void* d_ws, size_t ws_size,
                              hipStream_t stream) {
  const float* x = (const float*)d_in[0];
  const float* w = (const float*)d_in[1];
  const float* b = (const float*)d_in[2];
  float* o = (float*)d_out;
  hipLaunchKernelGGL(nlinear_mfma, dim3(1024), dim3(512), 0, stream, x, w, b, o);
}